// Round 13
// baseline (39.652 us; speedup 1.0000x reference)
//
#include <hip/hip_runtime.h>

// IDST (DST-III, x2) via four-step FFT (8192 = 32 x 32 x 8).
// R13 = R12 (real-row pairing, one block = 2 rows) + stall/inst cuts:
//  1) transpose-1: ONE twiddle chain walk computes both re-part (written
//     immediately) and im-part (kept in pB[32] regs, written in pass B) —
//     kills the 2nd __sincosf + 2nd serial 32-step complex-mul chain.
//  2) transpose-2 / DFT-8 reads / conj-exchange use an interleaved float2
//     plane (same 32KB): DS ops 320 -> 224, fewer addr calcs.

#define NN 4096

__device__ static constexpr float TW32R[16] = {
    1.0f, 0.98078528f, 0.92387953f, 0.83146961f,
    0.70710678f, 0.55557023f, 0.38268343f, 0.19509032f,
    0.0f, -0.19509032f, -0.38268343f, -0.55557023f,
    -0.70710678f, -0.83146961f, -0.92387953f, -0.98078528f};
__device__ static constexpr float TW32I[16] = {
    0.0f, 0.19509032f, 0.38268343f, 0.55557023f,
    0.70710678f, 0.83146961f, 0.92387953f, 0.98078528f,
    1.0f, 0.98078528f, 0.92387953f, 0.83146961f,
    0.70710678f, 0.55557023f, 0.38268343f, 0.19509032f};

__device__ __forceinline__ constexpr int brev5(int x) {
    return ((x & 1) << 4) | ((x & 2) << 2) | (x & 4) | ((x & 8) >> 2) | ((x & 16) >> 4);
}

// In-register 32-point DFT, sign +1 (inverse-FFT kernel), DIF.
// Output: X[k] sits at a[brev5(k)].
__device__ __forceinline__ void fft32(float (&re)[32], float (&im)[32]) {
#pragma unroll
    for (int len = 32; len >= 2; len >>= 1) {
        const int half = len >> 1;
#pragma unroll
        for (int base = 0; base < 32; base += len) {
#pragma unroll
            for (int o = 0; o < half; ++o) {
                const int tw = o * (32 / len);
                float ur = re[base + o], ui = im[base + o];
                float vr = re[base + o + half], vi = im[base + o + half];
                re[base + o] = ur + vr;
                im[base + o] = ui + vi;
                float dr = ur - vr, di = ui - vi;
                re[base + o + half] = dr * TW32R[tw] - di * TW32I[tw];
                im[base + o + half] = dr * TW32I[tw] + di * TW32R[tw];
            }
        }
    }
}

__global__ __launch_bounds__(256, 4) void idst_fft(const float* __restrict__ x,
                                                   const float2* __restrict__ expk,
                                                   float* __restrict__ y) {
    __shared__ float L[8224];            // 32.9 KB plane, time-multiplexed
    float2* const L2 = (float2*)L;       // interleaved view (4096 float2)

    const int j = threadIdx.x;
    const int blk = blockIdx.x;
    const float* xa = x + (size_t)(2 * blk) * NN;
    const float* xb = xa + NN;

    float cre[32], cim[32];

    // ---- Stage 1: b_n = a_n*(xa_n + j*xb_n)*e_n, n = 256*i + j; pad ----
#pragma unroll
    for (int i = 0; i < 16; ++i) {
        int n = j + 256 * i;
        float va = xa[n], vb = xb[n];
        if (n == NN - 1) { va *= 0.5f; vb *= 0.5f; }
        float2 e = expk[n];               // e_n = e.x + j*(-e.y)
        cre[i] = va * e.x + vb * e.y;
        cim[i] = vb * e.x - va * e.y;
    }
#pragma unroll
    for (int i = 16; i < 32; ++i) { cre[i] = 0.0f; cim[i] = 0.0f; }

    fft32(cre, cim);

    // ---- Transpose 1: single chain walk; re written now, im kept in pB ----
    float pB[32];
    {
        float ss, sc;
        __sincosf((float)j * 7.66990393943e-4f, &ss, &sc);   // 2*pi/8192
        float tr = 1.0f, ti = 0.0f;
#pragma unroll
        for (int k = 0; k < 32; ++k) {
            const int s = brev5(k);
            L[k * 257 + j] = cre[s] * tr - cim[s] * ti;
            pB[k]          = cre[s] * ti + cim[s] * tr;
            float nr = tr * sc - ti * ss;
            ti = tr * ss + ti * sc;
            tr = nr;
        }
    }
    __syncthreads();
    const int k1 = j & 31;
    const int c2 = j >> 5;
    float dre[32], dim2[32];
#pragma unroll
    for (int c1 = 0; c1 < 32; ++c1) dre[c1] = L[k1 * 257 + 8 * c1 + c2];
    __syncthreads();
#pragma unroll
    for (int k = 0; k < 32; ++k) L[k * 257 + j] = pB[k];
    __syncthreads();
#pragma unroll
    for (int c1 = 0; c1 < 32; ++c1) dim2[c1] = L[k1 * 257 + 8 * c1 + c2];
    __syncthreads();   // plane free for transpose 2

    fft32(dre, dim2);

    // ---- Transpose 2 + full DFT-8 per (k1, m1), two m1-halves ----
    const float R2 = 0.70710678f;
    float sr[4][8], si[4][8];     // [p = h*2+q][m2]  (all static indexing)

    float ss2, sc2;
    __sincosf((float)c2 * 2.45436926062e-2f, &ss2, &sc2);    // 2*pi/256
    float tr2 = 1.0f, ti2 = 0.0f;

#pragma unroll
    for (int h = 0; h < 2; ++h) {
        // write rows m1 = 16h .. 16h+15, interleaved float2
#pragma unroll
        for (int ml = 0; ml < 16; ++ml) {
            const int s = brev5(h * 16 + ml);
            L2[k1 + 32 * (ml * 8 + c2)] =
                make_float2(dre[s] * tr2 - dim2[s] * ti2,
                            dre[s] * ti2 + dim2[s] * tr2);
            float nr = tr2 * sc2 - ti2 * ss2;
            ti2 = tr2 * ss2 + ti2 * sc2;
            tr2 = nr;
        }
        __syncthreads();
        // all threads: DFT-8 for m1 = 16h + c2*2 + q, q = 0,1
#pragma unroll
        for (int q = 0; q < 2; ++q) {
            const int p = h * 2 + q;
            const int ml = c2 * 2 + q;
            float wre[8], wim[8];
#pragma unroll
            for (int c = 0; c < 8; ++c) {
                float2 v = L2[k1 + 32 * (ml * 8 + c)];
                wre[c] = v.x;
                wim[c] = v.y;
            }
            float t0r = wre[0] + wre[4], t0i = wim[0] + wim[4];
            float t1r = wre[0] - wre[4], t1i = wim[0] - wim[4];
            float t2r = wre[2] + wre[6], t2i = wim[2] + wim[6];
            float t3r = wre[2] - wre[6], t3i = wim[2] - wim[6];
            float E0r = t0r + t2r, E0i = t0i + t2i;
            float E2r = t0r - t2r, E2i = t0i - t2i;
            float E1r = t1r - t3i, E1i = t1i + t3r;
            float E3r = t1r + t3i, E3i = t1i - t3r;
            float u0r = wre[1] + wre[5], u0i = wim[1] + wim[5];
            float u1r = wre[1] - wre[5], u1i = wim[1] - wim[5];
            float u2r = wre[3] + wre[7], u2i = wim[3] + wim[7];
            float u3r = wre[3] - wre[7], u3i = wim[3] - wim[7];
            float O0r = u0r + u2r, O0i = u0i + u2i;
            float O2r = u0r - u2r, O2i = u0i - u2i;
            float O1r = u1r - u3i, O1i = u1i + u3r;
            float O3r = u1r + u3i, O3i = u1i - u3r;
            // g = w8^m2 * O
            float g1r = R2 * (O1r - O1i), g1i = R2 * (O1r + O1i);
            float g2r = -O2i,              g2i = O2r;
            float g3r = -R2 * (O3r + O3i), g3i = R2 * (O3r - O3i);

            sr[p][0] = E0r + O0r;  si[p][0] = E0i + O0i;
            sr[p][1] = E1r + g1r;  si[p][1] = E1i + g1i;
            sr[p][2] = E2r + g2r;  si[p][2] = E2i + g2i;
            sr[p][3] = E3r + g3r;  si[p][3] = E3i + g3i;
            sr[p][4] = E0r - O0r;  si[p][4] = E0i - O0i;
            sr[p][5] = E1r - g1r;  si[p][5] = E1i - g1i;
            sr[p][6] = E2r - g2r;  si[p][6] = E2i - g2i;
            sr[p][7] = E3r - g3r;  si[p][7] = E3i - g3i;
        }
        __syncthreads();
    }

    // ---- Exchange: publish S_z[k], k in [4096,8192), as float2 at k-4096 ----
#pragma unroll
    for (int p = 0; p < 4; ++p) {
        const int m1 = (p >> 1) * 16 + c2 * 2 + (p & 1);
#pragma unroll
        for (int m2 = 4; m2 < 8; ++m2) {
            L2[k1 + 32 * m1 + 1024 * (m2 - 4)] = make_float2(sr[p][m2], si[p][m2]);
        }
    }
    __syncthreads();

    // ---- Combine with conj partner + epilogue; write both rows ----
    const float2 e1v = expk[1];
    const float e1r = e1v.x, e1i = -e1v.y;
    float* ya = y + (size_t)(2 * blk) * NN;
    float* yb = ya + NN;

#pragma unroll
    for (int p = 0; p < 4; ++p) {
        const int m1 = (p >> 1) * 16 + c2 * 2 + (p & 1);
#pragma unroll
        for (int m2 = 0; m2 < 4; ++m2) {
            const int k = k1 + 32 * m1 + 1024 * m2;
            const float2 pv = L2[4095 - k];        // partner k' = 8191-k
            float2 ek = expk[k];
            const float er = ek.x, ei = -ek.y;     // e_k
            const float q2r = er * er - ei * ei;   // e_k^2
            const float q2i = 2.0f * er * ei;
            const float tkr = q2r * e1r - q2i * e1i;   // t_k = e_k^2 * e_1
            const float tki = q2r * e1i + q2i * e1r;
            const float urr = tkr * sr[p][m2] - tki * si[p][m2];  // u = t*Sz[k]
            const float uii = tkr * si[p][m2] + tki * sr[p][m2];
            const float vrr = tkr * pv.x + tki * pv.y;   // v = t*conj(Sz[k'])
            const float vii = tki * pv.x - tkr * pv.y;
            ya[k] = uii + vii;
            yb[k] = vrr - urr;
        }
    }
}

extern "C" void kernel_launch(void* const* d_in, const int* in_sizes, int n_in,
                              void* d_out, int out_size, void* d_ws, size_t ws_size,
                              hipStream_t stream) {
    const float*  x    = (const float*)d_in[0];
    const float2* expk = (const float2*)d_in[1];
    float* out = (float*)d_out;

    idst_fft<<<NN / 2, 256, 0, stream>>>(x, expk, out);
}